// Round 1
// 110.478 us; speedup vs baseline: 1.0154x; 1.0154x over previous
//
#include <hip/hip_runtime.h>

#define B 64
#define N 1024
#define E 16384
#define WPR 32          // words per adjacency row = N/32
#define NITER 5
#define CSR_SLOTS (E + N)   // even-aligned per-node alloc: <=1 pad slot/node
#define MAXP 20             // pair-words cached in registers (deg<=40 covered; LDS fallback beyond)

// ---- workspace layout (bytes) ---- (NO memset: feats/diag fully stored
// before any read; harness 0xAA poison harmless)
#define FEATS_OFF 0
#define DIAG_OFF  ((size_t)B * N * 4)

// R23: (a) single-pass 128KB LDS bitmask (gfx950 allows >64KB static LDS;
// kills 2 of 3 chunk passes + es/ed register staging); (b) pair-words cached
// in registers across the 5 WL iterations (iteration-invariant, removes 1/3
// of hot-loop LDS ops); (c) degree-descending counting-sort node->thread
// permutation so each wave is degree-homogeneous (hot loop trips: wave-max
// -> wave-mean). Rank machinery is R20's tested optimum, untouched.
__global__ void __launch_bounds__(1024) wl_mega_k(const int* __restrict__ src,
                                                  const int* __restrict__ dstp,
                                                  const int* __restrict__ lab0,
                                                  const float* __restrict__ hw,
                                                  unsigned int* __restrict__ feats,
                                                  float* __restrict__ diag) {
    __shared__ union {
        unsigned int chunk[N * WPR];                // Phase A1: 128KB full bitmask
        struct {
            unsigned short nbr[CSR_SLOTS];          // Phase A2/B: 34816B CSR
            struct {                                // Phase B: rank arrays 16KB
                int hist[N];
                int scan[N];
                float grp[N];
                int flag[N];
            } pb;
            int meta[N];                            // (start<<11)|deg per node
            unsigned short perm[N];                 // deg-sorted node order
            int dh[256];                            // deg histogram (clamped)
            int dtop[256];                          // descending alloc cursor
        } s;
    } u;
    __shared__ int s_lab[N + 2];                    // +sentinel slot (=0)
    __shared__ unsigned int s_feats[N];
    __shared__ int s_wsum[16];
    __shared__ int s_kp[16];
    __shared__ float s_mn[16], s_mx[16];
    __shared__ float s_gmn, s_gmx;
    __shared__ int s_K;
    __shared__ int s_anytie;
    int b = blockIdx.x, t = threadIdx.x;
    int lane = t & 63, w = t >> 6;

    // ---- Phase A0+A1: zero 128KB bitmask, labels to LDS ----
#pragma unroll
    for (int k = 0; k < 8; ++k)
        ((uint4*)u.chunk)[t + k * 1024] = make_uint4(0, 0, 0, 0);
    int l0 = lab0[(size_t)b * N + t];
    s_lab[t] = l0;
    s_feats[t] = 0;
    if (t == 0) { s_lab[N] = 0; s_anytie = 0; }
    __syncthreads();                                        // P0
    // init label bincount (labels < 16) via ballot
#pragma unroll
    for (int v = 0; v < 16; ++v) {
        unsigned long long m = __ballot(l0 == v);
        if (lane == v) {
            int c = __popcll(m);
            if (c) atomicAdd(&s_feats[v], (unsigned)c);
        }
    }

    // edge scatter: load + atomicOr in one pass (no register staging)
    const int* sg = src + (size_t)b * E;
    const int* dg_ = dstp + (size_t)b * E;
#pragma unroll
    for (int k = 0; k < 16; ++k) {                  // coalesced, 1 block/graph
        int es = sg[t + k * 1024];
        int ed = dg_[t + k * 1024];
        int wlog = ed >> 5;                         // logical word 0..31
        int g = wlog >> 2;                          // logical group 0..7
        int p = (g + es) & 7;                       // swizzled slot
        atomicOr(&u.chunk[es * WPR + p * 4 + (wlog & 3)], 1u << (ed & 31));
    }
    __syncthreads();                                        // C2
    uint4 r[8];
    {
        const uint4* row4 = (const uint4*)(u.chunk + t * WPR);
#pragma unroll
        for (int g = 0; g < 8; ++g)
            r[g] = row4[(g + t) & 7];               // conflict-free (swizzled)
    }
    __syncthreads();                                        // C3: chunk reusable

    // ---- Phase A2: deg/alloc/K/CSR starts + pack ----
    int dg = 0;
#pragma unroll
    for (int k = 0; k < 8; ++k)
        dg += __popc(r[k].x) + __popc(r[k].y) + __popc(r[k].z) + __popc(r[k].w);
    int alloc = (dg + 1) & ~1;                      // even per-node CSR alloc

    int f = alloc;                                  // wave scan of alloc
#pragma unroll
    for (int d2 = 1; d2 < 64; d2 <<= 1) {
        int v = __shfl_up(f, d2);
        if (lane >= d2) f += v;
    }
    int km = dg;
#pragma unroll
    for (int o = 32; o > 0; o >>= 1) km = max(km, __shfl_down(km, o));
    if (lane == 63) s_wsum[w] = f;
    if (lane == 0)  s_kp[w] = km;
    __syncthreads();                                        // A1
    if (w == 0) {                                   // wave0 shfl combine
        int orig = (lane < 16) ? s_wsum[lane] : 0;
        int v = orig;
#pragma unroll
        for (int d2 = 1; d2 < 16; d2 <<= 1) {
            int uu = __shfl_up(v, d2);
            if (lane >= d2) v += uu;
        }
        if (lane < 16) s_wsum[lane] = v - orig;     // exclusive wave base
        int kk = (lane < 16) ? s_kp[lane] : 0;
#pragma unroll
        for (int m2 = 8; m2 >= 1; m2 >>= 1) kk = max(kk, __shfl_xor(kk, m2));
        if (lane == 0) s_K = kk;
    }
    __syncthreads();                                        // A2
    int start = (f - alloc) + s_wsum[w];            // even => u32-aligned
    u.s.pb.hist[t] = 0;                             // aliases chunk: re-init
    u.s.pb.flag[t] = 0;
    if (t < 256) u.s.dh[t] = 0;

    // pack own row's set bits ONCE -> u16 list; pad odd deg with sentinel N
    {
        int idx = start;
#pragma unroll
        for (int k = 0; k < 8; ++k) {
            unsigned int wv[4] = { r[k].x, r[k].y, r[k].z, r[k].w };
#pragma unroll
            for (int c2 = 0; c2 < 4; ++c2) {
                unsigned int word = wv[c2];
                int bb = (k * 4 + c2) << 5;
                while (word) {
                    int j = __ffs(word) - 1;
                    word &= word - 1;
                    u.s.nbr[idx++] = (unsigned short)(bb + j);
                }
            }
        }
        if (dg & 1) u.s.nbr[idx] = (unsigned short)N;   // sentinel -> adds 0
    }
    u.s.meta[t] = (start << 11) | dg;               // start<2^15, dg<2^11
    float Kf = (float)s_K;
    float w0 = hw[0], w1 = hw[1];
    __syncthreads();                                        // A3

    // ---- Phase A3: degree-descending counting sort -> node perm ----
    atomicAdd(&u.s.dh[min(dg, 255)], 1);
    __syncthreads();                                        // A4
    if (w == 0) {                                   // 256-bin scan, 4/lane
        int h0 = u.s.dh[lane * 4], h1 = u.s.dh[lane * 4 + 1];
        int h2 = u.s.dh[lane * 4 + 2], h3 = u.s.dh[lane * 4 + 3];
        int c1 = h0 + h1, c2 = c1 + h2, c3 = c2 + h3;
        int ex = c3;
#pragma unroll
        for (int d2 = 1; d2 < 64; d2 <<= 1) {
            int v = __shfl_up(ex, d2);
            if (lane >= d2) ex += v;
        }
        ex -= c3;                                   // exclusive lane base
        // dtop[bin] = #nodes with deg > bin  (descending group start)
        u.s.dtop[lane * 4]     = N - (ex + h0);
        u.s.dtop[lane * 4 + 1] = N - (ex + c1);
        u.s.dtop[lane * 4 + 2] = N - (ex + c2);
        u.s.dtop[lane * 4 + 3] = N - (ex + c3);
    }
    __syncthreads();                                        // A5
    {
        int pos = atomicAdd(&u.s.dtop[min(dg, 255)], 1);
        u.s.perm[pos] = (unsigned short)t;
    }
    __syncthreads();                                        // A6
    int v_node = u.s.perm[t];                       // this thread's node
    int mv = u.s.meta[v_node];
    int vdeg = mv & 2047;
    int vpstart = (mv >> 11) >> 1;
    int vpairs = ((vdeg + 1) & ~1) >> 1;
    int lab_reg = s_lab[v_node];
    const unsigned int* nbr32 = (const unsigned int*)u.s.nbr;
    // iteration-invariant pair-words -> registers (static index = regs)
    unsigned int pw[MAXP];
#pragma unroll
    for (int k = 0; k < MAXP; ++k) {
        unsigned int pk = 0u;
        if (k < vpairs) pk = nbr32[vpstart + k];
        pw[k] = pk;
    }

    // ---- Phase B: 5 WL iterations (R12-proven machinery) ----
    for (int it = 0; it < NITER; ++it) {
        int ssum = 0;
#pragma unroll
        for (int k = 0; k < MAXP; ++k) if (k < vpairs) {
            unsigned int pr = pw[k];
            ssum += s_lab[pr & 0xFFFFu] + s_lab[pr >> 16];
        }
        for (int k = MAXP; k < vpairs; ++k) {       // rare high-deg fallback
            unsigned int pr = nbr32[vpstart + k];
            ssum += s_lab[pr & 0xFFFFu] + s_lab[pr >> 16];
        }
        float t1 = __fmul_rn(__fmul_rn(Kf, w0), (float)lab_reg);
        float t2 = __fmul_rn(w1, __fsub_rn(__fadd_rn((float)ssum, (float)vdeg), Kf));
        float h  = __fadd_rn(t1, t2);

        float mn = h, mx = h;
#pragma unroll
        for (int o = 32; o > 0; o >>= 1) {
            mn = fminf(mn, __shfl_down(mn, o));
            mx = fmaxf(mx, __shfl_down(mx, o));
        }
        if (lane == 0) { s_mn[w] = mn; s_mx[w] = mx; }
        __syncthreads();                                    // B1
        if (w == 0) {                                // wave0 shfl combine
            float a = (lane < 16) ? s_mn[lane] : 3.4e38f;
            float c = (lane < 16) ? s_mx[lane] : -3.4e38f;
#pragma unroll
            for (int m2 = 8; m2 >= 1; m2 >>= 1) {
                a = fminf(a, __shfl_xor(a, m2));
                c = fmaxf(c, __shfl_xor(c, m2));
            }
            if (lane == 0) { s_gmn = a; s_gmx = c; }
        }
        __syncthreads();                                    // B2
        float fmn = s_gmn;
        float span = s_gmx - fmn;
        float scale = (span > 0.f) ? (1023.0f / span) : 0.f;
        int bucket = min((int)((h - fmn) * scale), 1023);   // order-preserving
        int off_in = atomicAdd(&u.s.pb.hist[bucket], 1);
        __syncthreads();                                    // B3

        f = u.s.pb.hist[t];
#pragma unroll
        for (int d2 = 1; d2 < 64; d2 <<= 1) {
            int v = __shfl_up(f, d2);
            if (lane >= d2) f += v;
        }
        if (lane == 63) s_wsum[w] = f;
        __syncthreads();                                    // B4
        if (w == 0) {                                // wave0 shfl combine
            int orig = (lane < 16) ? s_wsum[lane] : 0;
            int v = orig;
#pragma unroll
            for (int d2 = 1; d2 < 16; d2 <<= 1) {
                int uu = __shfl_up(v, d2);
                if (lane >= d2) v += uu;
            }
            if (lane < 16) s_wsum[lane] = v - orig;  // exclusive
        }
        __syncthreads();                                    // B5
        u.s.pb.scan[t] = f + s_wsum[w];
        __syncthreads();                                    // B6

        int bs = u.s.pb.scan[bucket] - u.s.pb.hist[bucket];
        int be = u.s.pb.scan[bucket];
        u.s.pb.grp[bs + off_in] = h;
        __syncthreads();                                    // B7

        int c = bs;                 // lower buckets strictly less (monotone map)
        int eq = 0;
        for (int k = bs; k < be; ++k) {
            float g = u.s.pb.grp[k];
            c += (g < h);
            eq += (g == h);
        }
        if (eq > 1) s_anytie = it + 1;  // sentinel: stale iters self-invalidate
        u.s.pb.hist[t] = 0;             // re-zero for next iter
        __syncthreads();                                    // B8

        int rank;
        if (s_anytie != it + 1) {
            rank = c;                   // distinct keys: c IS the dense rank
            s_lab[v_node] = rank;
            lab_reg = rank;
            s_feats[rank] += 1u;        // permutation -> conflict-free
        } else {
            u.s.pb.flag[c] = 1;         // class start (same class -> same c)
            __syncthreads();                                // T1
            int f2 = u.s.pb.flag[t];
#pragma unroll
            for (int d2 = 1; d2 < 64; d2 <<= 1) {
                int v = __shfl_up(f2, d2);
                if (lane >= d2) f2 += v;
            }
            if (lane == 63) s_wsum[w] = f2;
            __syncthreads();                                // T2
            if (w == 0) {                            // wave0 shfl combine
                int orig = (lane < 16) ? s_wsum[lane] : 0;
                int v = orig;
#pragma unroll
                for (int d2 = 1; d2 < 16; d2 <<= 1) {
                    int uu = __shfl_up(v, d2);
                    if (lane >= d2) v += uu;
                }
                if (lane < 16) s_wsum[lane] = v - orig;
            }
            __syncthreads();                                // T3
            u.s.pb.scan[t] = f2 + s_wsum[w];
            u.s.pb.flag[t] = 0;         // own flag consumed above
            __syncthreads();                                // T4
            rank = u.s.pb.scan[c] - 1;
            s_lab[v_node] = rank;
            lab_reg = rank;
            atomicAdd(&s_feats[rank], 1u);
        }
        __syncthreads();                                    // B9
    }

    // ---- Phase C: feats out + fused diag[b] (int exact) ----
    unsigned int fv = s_feats[t];
    feats[(size_t)b * N + t] = fv;
    int sq = (int)(fv * fv);
#pragma unroll
    for (int o = 32; o > 0; o >>= 1) sq += __shfl_down(sq, o);
    if (lane == 0) s_wsum[w] = sq;
    __syncthreads();
    if (t == 0) {
        int tot = 0;
#pragma unroll
        for (int k = 0; k < 16; ++k) tot += s_wsum[k];
        diag[b] = (float)tot;
    }
}

// gram+normalize fused (measured ~4us): one block per row i; f_i staged in
// LDS; int dots exact; writes normalized value straight to d_out.
__global__ void __launch_bounds__(256) gram_k(const unsigned int* __restrict__ feats,
                                              const float* __restrict__ diag,
                                              float* __restrict__ out) {
    __shared__ unsigned int s_fi[N];
    int i = blockIdx.x, t = threadIdx.x;
    int lane = t & 63, w = t >> 6;
    ((uint4*)s_fi)[t] = ((const uint4*)(feats + (size_t)i * N))[t];
    __syncthreads();
    float di = diag[i];
    for (int jj = 0; jj < 16; ++jj) {
        int j = w * 16 + jj;
        const uint4* fj = (const uint4*)(feats + (size_t)j * N);
        const uint4* fi = (const uint4*)s_fi;
        int s = 0;
#pragma unroll
        for (int k = 0; k < 4; ++k) {
            uint4 vb = fj[lane + k * 64];
            uint4 va = fi[lane + k * 64];
            s += (int)(va.x * vb.x) + (int)(va.y * vb.y)
               + (int)(va.z * vb.z) + (int)(va.w * vb.w);
        }
#pragma unroll
        for (int off = 32; off > 0; off >>= 1) s += __shfl_down(s, off);
        if (lane == 0) out[i * B + j] = (float)s / sqrtf(di * diag[j]);
    }
}

extern "C" void kernel_launch(void* const* d_in, const int* in_sizes, int n_in,
                              void* d_out, int out_size, void* d_ws, size_t ws_size,
                              hipStream_t stream) {
    const int*   esrc = (const int*)d_in[0];
    const int*   edst = (const int*)d_in[1];
    const int*   lab0 = (const int*)d_in[2];
    const float* hw   = (const float*)d_in[3];

    char* ws = (char*)d_ws;
    unsigned int* feats = (unsigned int*)(ws + FEATS_OFF);
    float*        diag  = (float*)(ws + DIAG_OFF);

    wl_mega_k<<<B, 1024, 0, stream>>>(esrc, edst, lab0, hw, feats, diag);
    gram_k<<<B, 256, 0, stream>>>(feats, diag, (float*)d_out);
}

// Round 2
// 104.902 us; speedup vs baseline: 1.0693x; 1.0532x over previous
//
#include <hip/hip_runtime.h>

#define B 64
#define N 1024
#define E 16384
#define WPR 32          // words per adjacency row = N/32
#define NITER 5
#define CSR_SLOTS (E + N)   // even-aligned per-node alloc: <=1 pad slot/node
#define MAXP 20             // pair-words cached in registers (deg<=40 covered; LDS fallback beyond)

// ---- workspace layout (bytes) ---- (NO memset: feats/diag fully stored
// before any read; harness 0xAA poison harmless)
#define FEATS_OFF 0
#define DIAG_OFF  ((size_t)B * N * 4)

// R24: latency-chain attack (R23 showed conflicts are NOT critical path:
// -16% conflict cycles, flat time). (a) all block-wide reduces/scans now use
// ONE barrier: per-wave partials -> every wave redundantly combines 16
// partials via s_x[lane&15] broadcast-read + 4-step shfl_xor, result in a
// REGISTER (kills B2/B5/T3/A2 barriers + all wave0-idle serialization + the
// LDS broadcast round-trips). (b) no-tie iterations: ranks are a permutation
// => feats bincount is +1 everywhere => register counter, no LDS RMW.
// (c) edge loads hoisted to regs before the 128KB zero (L3 latency overlap).
__global__ void __launch_bounds__(1024) wl_mega_k(const int* __restrict__ src,
                                                  const int* __restrict__ dstp,
                                                  const int* __restrict__ lab0,
                                                  const float* __restrict__ hw,
                                                  unsigned int* __restrict__ feats,
                                                  float* __restrict__ diag) {
    __shared__ union {
        unsigned int chunk[N * WPR];                // Phase A1: 128KB full bitmask
        struct {
            unsigned short nbr[CSR_SLOTS];          // Phase A2/B: 34816B CSR
            struct {                                // Phase B: rank arrays 16KB
                int hist[N];
                int scan[N];
                float grp[N];
                int flag[N];
            } pb;
            int meta[N];                            // (start<<11)|deg per node
            unsigned short perm[N];                 // deg-sorted node order
            int dh[256];                            // deg histogram (clamped)
            int dtop[256];                          // descending alloc cursor
        } s;
    } u;
    __shared__ int s_lab[N + 2];                    // +sentinel slot (=0)
    __shared__ unsigned int s_feats[N];
    __shared__ int s_wsum[16];
    __shared__ int s_kp[16];
    __shared__ float s_mn[16], s_mx[16];
    __shared__ int s_anytie;
    int b = blockIdx.x, t = threadIdx.x;
    int lane = t & 63, w = t >> 6;

    // ---- Phase A0: edge loads first (L3 latency overlaps LDS zero) ----
    const int* sg = src + (size_t)b * E;
    const int* dg_ = dstp + (size_t)b * E;
    int es[16], ed[16];
#pragma unroll
    for (int k = 0; k < 16; ++k) {                  // coalesced, 1 block/graph
        es[k] = sg[t + k * 1024];
        ed[k] = dg_[t + k * 1024];
    }
    int l0 = lab0[(size_t)b * N + t];
    float w0 = hw[0], w1 = hw[1];
    // zero 128KB bitmask while loads are in flight
#pragma unroll
    for (int k = 0; k < 8; ++k)
        ((uint4*)u.chunk)[t + k * 1024] = make_uint4(0, 0, 0, 0);
    s_lab[t] = l0;
    s_feats[t] = 0;
    if (t == 0) { s_lab[N] = 0; s_anytie = 0; }
    __syncthreads();                                        // P0
    // init label bincount (labels < 16) via ballot
#pragma unroll
    for (int v = 0; v < 16; ++v) {
        unsigned long long m = __ballot(l0 == v);
        if (lane == v) {
            int c = __popcll(m);
            if (c) atomicAdd(&s_feats[v], (unsigned)c);
        }
    }

    // ---- Phase A1: bitmask scatter (swizzled), row -> r[8] ----
#pragma unroll
    for (int k = 0; k < 16; ++k) {
        int wlog = ed[k] >> 5;                      // logical word 0..31
        int g = wlog >> 2;                          // logical group 0..7
        int p = (g + es[k]) & 7;                    // swizzled slot
        atomicOr(&u.chunk[es[k] * WPR + p * 4 + (wlog & 3)], 1u << (ed[k] & 31));
    }
    __syncthreads();                                        // C2
    uint4 r[8];
    {
        const uint4* row4 = (const uint4*)(u.chunk + t * WPR);
#pragma unroll
        for (int g = 0; g < 8; ++g)
            r[g] = row4[(g + t) & 7];               // conflict-free (swizzled)
    }
    __syncthreads();                                        // C3: chunk reusable

    // ---- Phase A2: deg/alloc/K/CSR starts + pack ----
    int dg = 0;
#pragma unroll
    for (int k = 0; k < 8; ++k)
        dg += __popc(r[k].x) + __popc(r[k].y) + __popc(r[k].z) + __popc(r[k].w);
    int alloc = (dg + 1) & ~1;                      // even per-node CSR alloc

    int f = alloc;                                  // wave scan of alloc
#pragma unroll
    for (int d2 = 1; d2 < 64; d2 <<= 1) {
        int v = __shfl_up(f, d2);
        if (lane >= d2) f += v;
    }
    int km = dg;
#pragma unroll
    for (int o = 32; o > 0; o >>= 1) km = max(km, __shfl_down(km, o));
    if (lane == 63) s_wsum[w] = f;
    if (lane == 0)  s_kp[w] = km;
    __syncthreads();                                        // A1
    // all-wave redundant combine: wave-exclusive base + block K, in registers
    float Kf;
    int start;
    {
        int vv = ((lane & 15) < w) ? s_wsum[lane & 15] : 0;
#pragma unroll
        for (int m2 = 1; m2 < 16; m2 <<= 1) vv += __shfl_xor(vv, m2);
        start = (f - alloc) + vv;                   // even => u32-aligned
        int kk = s_kp[lane & 15];
#pragma unroll
        for (int m2 = 8; m2 >= 1; m2 >>= 1) kk = max(kk, __shfl_xor(kk, m2));
        Kf = (float)kk;
    }
    u.s.pb.hist[t] = 0;                             // aliases chunk: re-init
    u.s.pb.flag[t] = 0;
    if (t < 256) u.s.dh[t] = 0;

    // pack own row's set bits ONCE -> u16 list; pad odd deg with sentinel N
    {
        int idx = start;
#pragma unroll
        for (int k = 0; k < 8; ++k) {
            unsigned int wv[4] = { r[k].x, r[k].y, r[k].z, r[k].w };
#pragma unroll
            for (int c2 = 0; c2 < 4; ++c2) {
                unsigned int word = wv[c2];
                int bb = (k * 4 + c2) << 5;
                while (word) {
                    int j = __ffs(word) - 1;
                    word &= word - 1;
                    u.s.nbr[idx++] = (unsigned short)(bb + j);
                }
            }
        }
        if (dg & 1) u.s.nbr[idx] = (unsigned short)N;   // sentinel -> adds 0
    }
    u.s.meta[t] = (start << 11) | dg;               // start<2^15, dg<2^11
    __syncthreads();                                        // A3

    // ---- Phase A3: degree-descending counting sort -> node perm ----
    atomicAdd(&u.s.dh[min(dg, 255)], 1);
    __syncthreads();                                        // A4
    if (w == 0) {                                   // 256-bin scan, 4/lane
        int h0 = u.s.dh[lane * 4], h1 = u.s.dh[lane * 4 + 1];
        int h2 = u.s.dh[lane * 4 + 2], h3 = u.s.dh[lane * 4 + 3];
        int c1 = h0 + h1, c2 = c1 + h2, c3 = c2 + h3;
        int ex = c3;
#pragma unroll
        for (int d2 = 1; d2 < 64; d2 <<= 1) {
            int v = __shfl_up(ex, d2);
            if (lane >= d2) ex += v;
        }
        ex -= c3;                                   // exclusive lane base
        // dtop[bin] = #nodes with deg > bin  (descending group start)
        u.s.dtop[lane * 4]     = N - (ex + h0);
        u.s.dtop[lane * 4 + 1] = N - (ex + c1);
        u.s.dtop[lane * 4 + 2] = N - (ex + c2);
        u.s.dtop[lane * 4 + 3] = N - (ex + c3);
    }
    __syncthreads();                                        // A5
    {
        int pos = atomicAdd(&u.s.dtop[min(dg, 255)], 1);
        u.s.perm[pos] = (unsigned short)t;
    }
    __syncthreads();                                        // A6
    int v_node = u.s.perm[t];                       // this thread's node
    int mv = u.s.meta[v_node];
    int vdeg = mv & 2047;
    int vpstart = (mv >> 11) >> 1;
    int vpairs = ((vdeg + 1) & ~1) >> 1;
    int lab_reg = s_lab[v_node];
    const unsigned int* nbr32 = (const unsigned int*)u.s.nbr;
    // iteration-invariant pair-words -> registers (static index = regs)
    unsigned int pw[MAXP];
#pragma unroll
    for (int k = 0; k < MAXP; ++k) {
        unsigned int pk = 0u;
        if (k < vpairs) pk = nbr32[vpstart + k];
        pw[k] = pk;
    }

    // ---- Phase B: 5 WL iterations ----
    int nfast = 0;                                  // fast-path feats counter
    for (int it = 0; it < NITER; ++it) {
        int ssum = 0;
#pragma unroll
        for (int k = 0; k < MAXP; ++k) if (k < vpairs) {
            unsigned int pr = pw[k];
            ssum += s_lab[pr & 0xFFFFu] + s_lab[pr >> 16];
        }
        for (int k = MAXP; k < vpairs; ++k) {       // rare high-deg fallback
            unsigned int pr = nbr32[vpstart + k];
            ssum += s_lab[pr & 0xFFFFu] + s_lab[pr >> 16];
        }
        float t1 = __fmul_rn(__fmul_rn(Kf, w0), (float)lab_reg);
        float t2 = __fmul_rn(w1, __fsub_rn(__fadd_rn((float)ssum, (float)vdeg), Kf));
        float h  = __fadd_rn(t1, t2);

        float mn = h, mx = h;
#pragma unroll
        for (int o = 32; o > 0; o >>= 1) {
            mn = fminf(mn, __shfl_down(mn, o));
            mx = fmaxf(mx, __shfl_down(mx, o));
        }
        if (lane == 0) { s_mn[w] = mn; s_mx[w] = mx; }
        __syncthreads();                                    // B1
        // all-wave redundant min/max combine -> registers (no 2nd barrier)
        float fmn, span;
        {
            float a = s_mn[lane & 15];
            float cmx = s_mx[lane & 15];
#pragma unroll
            for (int m2 = 8; m2 >= 1; m2 >>= 1) {
                a = fminf(a, __shfl_xor(a, m2));
                cmx = fmaxf(cmx, __shfl_xor(cmx, m2));
            }
            fmn = a;
            span = cmx - a;
        }
        float scale = (span > 0.f) ? (1023.0f / span) : 0.f;
        int bucket = min((int)((h - fmn) * scale), 1023);   // order-preserving
        int off_in = atomicAdd(&u.s.pb.hist[bucket], 1);
        __syncthreads();                                    // B3

        f = u.s.pb.hist[t];
#pragma unroll
        for (int d2 = 1; d2 < 64; d2 <<= 1) {
            int v = __shfl_up(f, d2);
            if (lane >= d2) f += v;
        }
        if (lane == 63) s_wsum[w] = f;
        __syncthreads();                                    // B4
        {   // all-wave redundant exclusive wave base -> register
            int vv = ((lane & 15) < w) ? s_wsum[lane & 15] : 0;
#pragma unroll
            for (int m2 = 1; m2 < 16; m2 <<= 1) vv += __shfl_xor(vv, m2);
            u.s.pb.scan[t] = f + vv;
        }
        __syncthreads();                                    // B6

        int bs = u.s.pb.scan[bucket] - u.s.pb.hist[bucket];
        int be = u.s.pb.scan[bucket];
        u.s.pb.grp[bs + off_in] = h;
        __syncthreads();                                    // B7

        int cr = bs;                // lower buckets strictly less (monotone map)
        int eq = 0;
        for (int k = bs; k < be; ++k) {
            float g = u.s.pb.grp[k];
            cr += (g < h);
            eq += (g == h);
        }
        if (eq > 1) s_anytie = it + 1;  // sentinel: stale iters self-invalidate
        u.s.pb.hist[t] = 0;             // re-zero for next iter
        __syncthreads();                                    // B8

        if (s_anytie != it + 1) {
            // distinct keys: cr IS the dense rank; ranks are a permutation
            // of 0..N-1 => every feats bin gets +1 => register counter.
            s_lab[v_node] = cr;
            lab_reg = cr;
            ++nfast;
        } else {
            u.s.pb.flag[cr] = 1;        // class start (same class -> same cr)
            __syncthreads();                                // T1
            int f2 = u.s.pb.flag[t];
#pragma unroll
            for (int d2 = 1; d2 < 64; d2 <<= 1) {
                int v = __shfl_up(f2, d2);
                if (lane >= d2) f2 += v;
            }
            if (lane == 63) s_wsum[w] = f2;
            __syncthreads();                                // T2
            {   // all-wave redundant exclusive wave base -> register
                int vv = ((lane & 15) < w) ? s_wsum[lane & 15] : 0;
#pragma unroll
                for (int m2 = 1; m2 < 16; m2 <<= 1) vv += __shfl_xor(vv, m2);
                u.s.pb.scan[t] = f2 + vv;
            }
            u.s.pb.flag[t] = 0;         // own flag consumed above
            __syncthreads();                                // T4
            int rank = u.s.pb.scan[cr] - 1;
            s_lab[v_node] = rank;
            lab_reg = rank;
            atomicAdd(&s_feats[rank], 1u);
        }
        __syncthreads();                                    // B9
    }

    // ---- Phase C: feats out + fused diag[b] (int exact) ----
    unsigned int fv = s_feats[t] + (unsigned)nfast;
    feats[(size_t)b * N + t] = fv;
    int sq = (int)(fv * fv);
#pragma unroll
    for (int o = 32; o > 0; o >>= 1) sq += __shfl_down(sq, o);
    if (lane == 0) s_wsum[w] = sq;
    __syncthreads();
    if (t == 0) {
        int tot = 0;
#pragma unroll
        for (int k = 0; k < 16; ++k) tot += s_wsum[k];
        diag[b] = (float)tot;
    }
}

// gram+normalize fused (measured ~4us): one block per row i; f_i staged in
// LDS; int dots exact; writes normalized value straight to d_out.
__global__ void __launch_bounds__(256) gram_k(const unsigned int* __restrict__ feats,
                                              const float* __restrict__ diag,
                                              float* __restrict__ out) {
    __shared__ unsigned int s_fi[N];
    int i = blockIdx.x, t = threadIdx.x;
    int lane = t & 63, w = t >> 6;
    ((uint4*)s_fi)[t] = ((const uint4*)(feats + (size_t)i * N))[t];
    __syncthreads();
    float di = diag[i];
    for (int jj = 0; jj < 16; ++jj) {
        int j = w * 16 + jj;
        const uint4* fj = (const uint4*)(feats + (size_t)j * N);
        const uint4* fi = (const uint4*)s_fi;
        int s = 0;
#pragma unroll
        for (int k = 0; k < 4; ++k) {
            uint4 vb = fj[lane + k * 64];
            uint4 va = fi[lane + k * 64];
            s += (int)(va.x * vb.x) + (int)(va.y * vb.y)
               + (int)(va.z * vb.z) + (int)(va.w * vb.w);
        }
#pragma unroll
        for (int off = 32; off > 0; off >>= 1) s += __shfl_down(s, off);
        if (lane == 0) out[i * B + j] = (float)s / sqrtf(di * diag[j]);
    }
}

extern "C" void kernel_launch(void* const* d_in, const int* in_sizes, int n_in,
                              void* d_out, int out_size, void* d_ws, size_t ws_size,
                              hipStream_t stream) {
    const int*   esrc = (const int*)d_in[0];
    const int*   edst = (const int*)d_in[1];
    const int*   lab0 = (const int*)d_in[2];
    const float* hw   = (const float*)d_in[3];

    char* ws = (char*)d_ws;
    unsigned int* feats = (unsigned int*)(ws + FEATS_OFF);
    float*        diag  = (float*)(ws + DIAG_OFF);

    wl_mega_k<<<B, 1024, 0, stream>>>(esrc, edst, lab0, hw, feats, diag);
    gram_k<<<B, 256, 0, stream>>>(feats, diag, (float*)d_out);
}

// Round 3
// 99.250 us; speedup vs baseline: 1.1302x; 1.0569x over previous
//
#include <hip/hip_runtime.h>

#define B 64
#define N 1024
#define E 16384
#define WPR 32          // words per adjacency row = N/32
#define NITER 5
#define CSR_SLOTS (E + N)   // even-aligned per-node alloc: <=1 pad slot/node
#define MAXP 20             // pair-words cached in registers (deg<=40; LDS fallback beyond)
#define SENT_PAIR 0x04000400u   // (N<<16)|N : both halves index s_lab[N]==0

// ---- workspace layout (bytes) ---- (NO memset: feats/diag fully stored
// before any read; harness 0xAA poison harmless)
#define FEATS_OFF 0
#define DIAG_OFF  ((size_t)B * N * 4)

// R25: (a) counting sort REMOVED — the unrolled predicated gather pays all
// MAXP slots per wave anyway, so deg-homogeneity bought nothing; removal
// saves 3 barriers + atomics + the perm indirection (s_lab writes now
// contiguous). (b) pw[] padded with sentinel pairs -> hot gather is 20
// UNCONDITIONAL reads (no exec-mask churn); s_lab[N]=0 absorbs them.
// (c) B8 deleted: optimistic fast-path rank write, tie check deferred past
// B9 (uniform), rare repair pass after. 6 barriers/iter (was 7).
// (d) gram_k: 16 waves x 4 j's (serial chain 16 -> 4 iterations).
__global__ void __launch_bounds__(1024) wl_mega_k(const int* __restrict__ src,
                                                  const int* __restrict__ dstp,
                                                  const int* __restrict__ lab0,
                                                  const float* __restrict__ hw,
                                                  unsigned int* __restrict__ feats,
                                                  float* __restrict__ diag) {
    __shared__ union {
        unsigned int chunk[N * WPR];                // Phase A1: 128KB full bitmask
        struct {
            unsigned short nbr[CSR_SLOTS];          // Phase A2/B: 34816B CSR (self-read only)
            struct {                                // Phase B: rank arrays 16KB
                int hist[N];
                int scan[N];
                float grp[N];
                int flag[N];
            } pb;
        } s;
    } u;
    __shared__ int s_lab[N + 2];                    // +sentinel slot (=0)
    __shared__ unsigned int s_feats[N];
    __shared__ int s_wsum[16];
    __shared__ int s_kp[16];
    __shared__ float s_mn[16], s_mx[16];
    __shared__ int s_anytie;
    int b = blockIdx.x, t = threadIdx.x;
    int lane = t & 63, w = t >> 6;

    // ---- Phase A0: edge loads first (L3 latency overlaps LDS zero) ----
    const int* sg = src + (size_t)b * E;
    const int* dg_ = dstp + (size_t)b * E;
    int es[16], ed[16];
#pragma unroll
    for (int k = 0; k < 16; ++k) {                  // coalesced, 1 block/graph
        es[k] = sg[t + k * 1024];
        ed[k] = dg_[t + k * 1024];
    }
    int l0 = lab0[(size_t)b * N + t];
    float w0 = hw[0], w1 = hw[1];
    // zero 128KB bitmask while loads are in flight
#pragma unroll
    for (int k = 0; k < 8; ++k)
        ((uint4*)u.chunk)[t + k * 1024] = make_uint4(0, 0, 0, 0);
    s_lab[t] = l0;
    s_feats[t] = 0;
    if (t == 0) { s_lab[N] = 0; s_anytie = 0; }
    __syncthreads();                                        // P0
    // init label bincount (labels < 16) via ballot
#pragma unroll
    for (int v = 0; v < 16; ++v) {
        unsigned long long m = __ballot(l0 == v);
        if (lane == v) {
            int c = __popcll(m);
            if (c) atomicAdd(&s_feats[v], (unsigned)c);
        }
    }

    // ---- Phase A1: bitmask scatter (swizzled), row -> r[8] ----
#pragma unroll
    for (int k = 0; k < 16; ++k) {
        int wlog = ed[k] >> 5;                      // logical word 0..31
        int g = wlog >> 2;                          // logical group 0..7
        int p = (g + es[k]) & 7;                    // swizzled slot
        atomicOr(&u.chunk[es[k] * WPR + p * 4 + (wlog & 3)], 1u << (ed[k] & 31));
    }
    __syncthreads();                                        // C2
    uint4 r[8];
    {
        const uint4* row4 = (const uint4*)(u.chunk + t * WPR);
#pragma unroll
        for (int g = 0; g < 8; ++g)
            r[g] = row4[(g + t) & 7];               // conflict-free (swizzled)
    }
    __syncthreads();                                        // C3: chunk reusable

    // ---- Phase A2: deg/alloc/K/CSR starts + pack ----
    int dg = 0;
#pragma unroll
    for (int k = 0; k < 8; ++k)
        dg += __popc(r[k].x) + __popc(r[k].y) + __popc(r[k].z) + __popc(r[k].w);
    int alloc = (dg + 1) & ~1;                      // even per-node CSR alloc

    int f = alloc;                                  // wave scan of alloc
#pragma unroll
    for (int d2 = 1; d2 < 64; d2 <<= 1) {
        int v = __shfl_up(f, d2);
        if (lane >= d2) f += v;
    }
    int km = dg;
#pragma unroll
    for (int o = 32; o > 0; o >>= 1) km = max(km, __shfl_down(km, o));
    if (lane == 63) s_wsum[w] = f;
    if (lane == 0)  s_kp[w] = km;
    __syncthreads();                                        // A1
    // all-wave redundant combine: wave-exclusive base + block K, in registers
    float Kf;
    int start;
    {
        int vv = ((lane & 15) < w) ? s_wsum[lane & 15] : 0;
#pragma unroll
        for (int m2 = 1; m2 < 16; m2 <<= 1) vv += __shfl_xor(vv, m2);
        start = (f - alloc) + vv;                   // even => u32-aligned
        int kk = s_kp[lane & 15];
#pragma unroll
        for (int m2 = 8; m2 >= 1; m2 >>= 1) kk = max(kk, __shfl_xor(kk, m2));
        Kf = (float)kk;
    }
    u.s.pb.hist[t] = 0;                             // aliases chunk: re-init
    u.s.pb.flag[t] = 0;

    // pack own row's set bits ONCE -> u16 list; pad odd deg with sentinel N
    {
        int idx = start;
#pragma unroll
        for (int k = 0; k < 8; ++k) {
            unsigned int wv[4] = { r[k].x, r[k].y, r[k].z, r[k].w };
#pragma unroll
            for (int c2 = 0; c2 < 4; ++c2) {
                unsigned int word = wv[c2];
                int bb = (k * 4 + c2) << 5;
                while (word) {
                    int j = __ffs(word) - 1;
                    word &= word - 1;
                    u.s.nbr[idx++] = (unsigned short)(bb + j);
                }
            }
        }
        if (dg & 1) u.s.nbr[idx] = (unsigned short)N;   // sentinel -> adds 0
    }
    __syncthreads();                                        // A3 (pack->preload order)

    int vdeg = dg;
    int vpstart = start >> 1;
    int vpairs = alloc >> 1;
    int lab_reg = l0;
    const unsigned int* nbr32 = (const unsigned int*)u.s.nbr;
    // iteration-invariant pair-words -> registers; sentinel-pad to MAXP so
    // the hot loop needs NO predication (sentinel reads broadcast s_lab[N]=0)
    unsigned int pw[MAXP];
#pragma unroll
    for (int k = 0; k < MAXP; ++k)
        pw[k] = (k < vpairs) ? nbr32[vpstart + k] : SENT_PAIR;

    // ---- Phase B: 5 WL iterations ----
    int nfast = 0;                                  // fast-path feats counter
    for (int it = 0; it < NITER; ++it) {
        int ssum = 0;
#pragma unroll
        for (int k = 0; k < MAXP; ++k) {            // unconditional: 40 gathers
            unsigned int pr = pw[k];
            ssum += s_lab[pr & 0xFFFFu] + s_lab[pr >> 16];
        }
        for (int k = MAXP; k < vpairs; ++k) {       // rare high-deg fallback
            unsigned int pr = nbr32[vpstart + k];
            ssum += s_lab[pr & 0xFFFFu] + s_lab[pr >> 16];
        }
        float t1 = __fmul_rn(__fmul_rn(Kf, w0), (float)lab_reg);
        float t2 = __fmul_rn(w1, __fsub_rn(__fadd_rn((float)ssum, (float)vdeg), Kf));
        float h  = __fadd_rn(t1, t2);

        float mn = h, mx = h;
#pragma unroll
        for (int o = 32; o > 0; o >>= 1) {
            mn = fminf(mn, __shfl_down(mn, o));
            mx = fmaxf(mx, __shfl_down(mx, o));
        }
        if (lane == 0) { s_mn[w] = mn; s_mx[w] = mx; }
        __syncthreads();                                    // B1
        // all-wave redundant min/max combine -> registers (no 2nd barrier)
        float fmn, span;
        {
            float a = s_mn[lane & 15];
            float cmx = s_mx[lane & 15];
#pragma unroll
            for (int m2 = 8; m2 >= 1; m2 >>= 1) {
                a = fminf(a, __shfl_xor(a, m2));
                cmx = fmaxf(cmx, __shfl_xor(cmx, m2));
            }
            fmn = a;
            span = cmx - a;
        }
        float scale = (span > 0.f) ? (1023.0f / span) : 0.f;
        int bucket = min((int)((h - fmn) * scale), 1023);   // order-preserving
        int off_in = atomicAdd(&u.s.pb.hist[bucket], 1);
        __syncthreads();                                    // B3

        f = u.s.pb.hist[t];
#pragma unroll
        for (int d2 = 1; d2 < 64; d2 <<= 1) {
            int v = __shfl_up(f, d2);
            if (lane >= d2) f += v;
        }
        if (lane == 63) s_wsum[w] = f;
        __syncthreads();                                    // B4
        {   // all-wave redundant exclusive wave base -> register
            int vv = ((lane & 15) < w) ? s_wsum[lane & 15] : 0;
#pragma unroll
            for (int m2 = 1; m2 < 16; m2 <<= 1) vv += __shfl_xor(vv, m2);
            u.s.pb.scan[t] = f + vv;
        }
        __syncthreads();                                    // B6

        int bs = u.s.pb.scan[bucket] - u.s.pb.hist[bucket];
        int be = u.s.pb.scan[bucket];
        u.s.pb.grp[bs + off_in] = h;
        __syncthreads();                                    // B7

        int cr = bs;                // lower buckets strictly less (monotone map)
        int eq = 0;
        for (int k = bs; k < be; ++k) {
            float g = u.s.pb.grp[k];
            cr += (g < h);
            eq += (g == h);
        }
        if (eq > 1) s_anytie = it + 1;  // sentinel: stale iters self-invalidate
        u.s.pb.hist[t] = 0;             // re-zero for next iter (readers done pre-B7)
        s_lab[t] = cr;                  // optimistic fast-path rank (dense iff no ties)
        __syncthreads();                                    // B9
        if (s_anytie == it + 1) {       // rare: dense-rank repair pass
            u.s.pb.flag[cr] = 1;        // class start (same class -> same cr)
            __syncthreads();                                // T1
            int f2 = u.s.pb.flag[t];
#pragma unroll
            for (int d2 = 1; d2 < 64; d2 <<= 1) {
                int v = __shfl_up(f2, d2);
                if (lane >= d2) f2 += v;
            }
            if (lane == 63) s_wsum[w] = f2;
            __syncthreads();                                // T2
            {   // all-wave redundant exclusive wave base -> register
                int vv = ((lane & 15) < w) ? s_wsum[lane & 15] : 0;
#pragma unroll
                for (int m2 = 1; m2 < 16; m2 <<= 1) vv += __shfl_xor(vv, m2);
                u.s.pb.scan[t] = f2 + vv;
            }
            u.s.pb.flag[t] = 0;         // own flag consumed above
            __syncthreads();                                // T4
            int rank = u.s.pb.scan[cr] - 1;
            s_lab[t] = rank;
            lab_reg = rank;
            atomicAdd(&s_feats[rank], 1u);
            __syncthreads();                                // T5: labels visible
        } else {
            lab_reg = cr;
            ++nfast;                    // permutation => every bin +1
        }
    }

    // ---- Phase C: feats out + fused diag[b] (int exact) ----
    unsigned int fv = s_feats[t] + (unsigned)nfast;
    feats[(size_t)b * N + t] = fv;
    int sq = (int)(fv * fv);
#pragma unroll
    for (int o = 32; o > 0; o >>= 1) sq += __shfl_down(sq, o);
    if (lane == 0) s_wsum[w] = sq;
    __syncthreads();
    if (t == 0) {
        int tot = 0;
#pragma unroll
        for (int k = 0; k < 16; ++k) tot += s_wsum[k];
        diag[b] = (float)tot;
    }
}

// gram+normalize fused: one block per row i; f_i staged in LDS; int dots
// exact. R25: 1024 threads, 16 waves x 4 j's each (serial chain 16 -> 4).
__global__ void __launch_bounds__(1024) gram_k(const unsigned int* __restrict__ feats,
                                               const float* __restrict__ diag,
                                               float* __restrict__ out) {
    __shared__ unsigned int s_fi[N];
    int i = blockIdx.x, t = threadIdx.x;
    int lane = t & 63, w = t >> 6;
    if (t < 256)
        ((uint4*)s_fi)[t] = ((const uint4*)(feats + (size_t)i * N))[t];
    __syncthreads();
    float di = diag[i];
#pragma unroll
    for (int jj = 0; jj < 4; ++jj) {
        int j = w * 4 + jj;
        const uint4* fj = (const uint4*)(feats + (size_t)j * N);
        const uint4* fi = (const uint4*)s_fi;
        int s = 0;
#pragma unroll
        for (int k = 0; k < 4; ++k) {
            uint4 vb = fj[lane + k * 64];
            uint4 va = fi[lane + k * 64];
            s += (int)(va.x * vb.x) + (int)(va.y * vb.y)
               + (int)(va.z * vb.z) + (int)(va.w * vb.w);
        }
#pragma unroll
        for (int off = 32; off > 0; off >>= 1) s += __shfl_down(s, off);
        if (lane == 0) out[i * B + j] = (float)s / sqrtf(di * diag[j]);
    }
}

extern "C" void kernel_launch(void* const* d_in, const int* in_sizes, int n_in,
                              void* d_out, int out_size, void* d_ws, size_t ws_size,
                              hipStream_t stream) {
    const int*   esrc = (const int*)d_in[0];
    const int*   edst = (const int*)d_in[1];
    const int*   lab0 = (const int*)d_in[2];
    const float* hw   = (const float*)d_in[3];

    char* ws = (char*)d_ws;
    unsigned int* feats = (unsigned int*)(ws + FEATS_OFF);
    float*        diag  = (float*)(ws + DIAG_OFF);

    wl_mega_k<<<B, 1024, 0, stream>>>(esrc, edst, lab0, hw, feats, diag);
    gram_k<<<B, 1024, 0, stream>>>(feats, diag, (float*)d_out);
}

// Round 4
// 98.854 us; speedup vs baseline: 1.1347x; 1.0040x over previous
//
#include <hip/hip_runtime.h>

#define B 64
#define N 1024
#define E 16384
#define WPR 32          // words per adjacency row = N/32
#define NITER 5
#define CSR_SLOTS (E + N)   // even-aligned per-node alloc: <=1 pad slot/node
#define MAXP 20             // pair-words cached in registers (deg<=40; LDS fallback beyond)
#define SENT_PAIR 0x04000400u   // (N<<16)|N : both halves index s_lab[N]==0

// ---- workspace layout (bytes) ---- (NO memset: feats/diag fully stored
// before any read; harness 0xAA poison harmless)
#define FEATS_OFF 0
#define DIAG_OFF  ((size_t)B * N * 4)

// R26: wave-uniform chunk skipping on the hot gather. Mean pairs = 8 but R25
// paid all MAXP=20 slots (40 gathers/thread, 2.4x waste). Fix: 5 chunks of
// 4 pairs, skipped on a readfirstlane-uniform `c*4 < wave_max_pairs`
// (s_cbranch, no exec-mask churn) + degree-descending counting sort so
// wave_max ~= wave_mean (gathers ~640 -> ~340 wave-inst/iter). Sort is
// nearly free this time: dh/dtop OUTSIDE the union (zeroed at A0 under the
// bitmask's lifetime), within-bin pos from the dh atomicAdd return, 256-bin
// scan rides wave0 in the existing A1 window, dtop/meta publication rides
// the existing A3 barrier => only +1 barrier (perm visibility).
__global__ void __launch_bounds__(1024) wl_mega_k(const int* __restrict__ src,
                                                  const int* __restrict__ dstp,
                                                  const int* __restrict__ lab0,
                                                  const float* __restrict__ hw,
                                                  unsigned int* __restrict__ feats,
                                                  float* __restrict__ diag) {
    __shared__ union {
        unsigned int chunk[N * WPR];                // Phase A1: 128KB full bitmask
        struct {
            unsigned short nbr[CSR_SLOTS];          // Phase A2/B: 34816B CSR
            struct {                                // Phase B: rank arrays 16KB
                int hist[N];
                int scan[N];
                float grp[N];
                int flag[N];
            } pb;
            int meta[N];                            // (start<<11)|deg per node
            unsigned short perm[N];                 // deg-sorted node order
        } s;
    } u;
    __shared__ int s_lab[N + 2];                    // +sentinel slot (=0)
    __shared__ unsigned int s_feats[N];
    __shared__ int s_wsum[16];
    __shared__ int s_kp[16];
    __shared__ float s_mn[16], s_mx[16];
    __shared__ int s_anytie;
    __shared__ int s_dh[256];                       // deg histogram (outside union:
    __shared__ int s_dtop[256];                     //  zeroed while bitmask lives)
    int b = blockIdx.x, t = threadIdx.x;
    int lane = t & 63, w = t >> 6;

    // ---- Phase A0: edge loads first (L3 latency overlaps LDS zero) ----
    const int* sg = src + (size_t)b * E;
    const int* dg_ = dstp + (size_t)b * E;
    int es[16], ed[16];
#pragma unroll
    for (int k = 0; k < 16; ++k) {                  // coalesced, 1 block/graph
        es[k] = sg[t + k * 1024];
        ed[k] = dg_[t + k * 1024];
    }
    int l0 = lab0[(size_t)b * N + t];
    float w0 = hw[0], w1 = hw[1];
    // zero 128KB bitmask while loads are in flight
#pragma unroll
    for (int k = 0; k < 8; ++k)
        ((uint4*)u.chunk)[t + k * 1024] = make_uint4(0, 0, 0, 0);
    s_lab[t] = l0;
    s_feats[t] = 0;
    if (t < 256) s_dh[t] = 0;
    if (t == 0) { s_lab[N] = 0; s_anytie = 0; }
    __syncthreads();                                        // P0
    // init label bincount (labels < 16) via ballot
#pragma unroll
    for (int v = 0; v < 16; ++v) {
        unsigned long long m = __ballot(l0 == v);
        if (lane == v) {
            int c = __popcll(m);
            if (c) atomicAdd(&s_feats[v], (unsigned)c);
        }
    }

    // ---- Phase A1: bitmask scatter (swizzled), row -> r[8] ----
#pragma unroll
    for (int k = 0; k < 16; ++k) {
        int wlog = ed[k] >> 5;                      // logical word 0..31
        int g = wlog >> 2;                          // logical group 0..7
        int p = (g + es[k]) & 7;                    // swizzled slot
        atomicOr(&u.chunk[es[k] * WPR + p * 4 + (wlog & 3)], 1u << (ed[k] & 31));
    }
    __syncthreads();                                        // C2
    uint4 r[8];
    {
        const uint4* row4 = (const uint4*)(u.chunk + t * WPR);
#pragma unroll
        for (int g = 0; g < 8; ++g)
            r[g] = row4[(g + t) & 7];               // conflict-free (swizzled)
    }
    __syncthreads();                                        // C3: chunk reusable

    // ---- Phase A2: deg/alloc/K/CSR starts + pack + sort bookkeeping ----
    int dg = 0;
#pragma unroll
    for (int k = 0; k < 8; ++k)
        dg += __popc(r[k].x) + __popc(r[k].y) + __popc(r[k].z) + __popc(r[k].w);
    int dbin = min(dg, 255);
    int pib = atomicAdd(&s_dh[dbin], 1);            // within-bin position (free)
    int alloc = (dg + 1) & ~1;                      // even per-node CSR alloc

    int f = alloc;                                  // wave scan of alloc
#pragma unroll
    for (int d2 = 1; d2 < 64; d2 <<= 1) {
        int v = __shfl_up(f, d2);
        if (lane >= d2) f += v;
    }
    int km = dg;
#pragma unroll
    for (int o = 32; o > 0; o >>= 1) km = max(km, __shfl_down(km, o));
    if (lane == 63) s_wsum[w] = f;
    if (lane == 0)  s_kp[w] = km;
    __syncthreads();                                        // A1 (covers dh atomics)
    // all-wave redundant combine: wave-exclusive base + block K, in registers
    float Kf;
    int start;
    {
        int vv = ((lane & 15) < w) ? s_wsum[lane & 15] : 0;
#pragma unroll
        for (int m2 = 1; m2 < 16; m2 <<= 1) vv += __shfl_xor(vv, m2);
        start = (f - alloc) + vv;                   // even => u32-aligned
        int kk = s_kp[lane & 15];
#pragma unroll
        for (int m2 = 8; m2 >= 1; m2 >>= 1) kk = max(kk, __shfl_xor(kk, m2));
        Kf = (float)kk;
    }
    if (w == 0) {                                   // 256-bin descending starts
        int h0 = s_dh[lane * 4], h1 = s_dh[lane * 4 + 1];
        int h2 = s_dh[lane * 4 + 2], h3 = s_dh[lane * 4 + 3];
        int c1 = h0 + h1, c2 = c1 + h2, c3 = c2 + h3;
        int ex = c3;
#pragma unroll
        for (int d2 = 1; d2 < 64; d2 <<= 1) {
            int v = __shfl_up(ex, d2);
            if (lane >= d2) ex += v;
        }
        ex -= c3;                                   // exclusive lane base
        // dtop[bin] = #nodes with deg > bin  (descending group start)
        s_dtop[lane * 4]     = N - (ex + h0);
        s_dtop[lane * 4 + 1] = N - (ex + c1);
        s_dtop[lane * 4 + 2] = N - (ex + c2);
        s_dtop[lane * 4 + 3] = N - (ex + c3);
    }
    u.s.pb.hist[t] = 0;                             // aliases chunk: re-init
    u.s.pb.flag[t] = 0;

    // pack own row's set bits ONCE -> u16 list; pad odd deg with sentinel N
    {
        int idx = start;
#pragma unroll
        for (int k = 0; k < 8; ++k) {
            unsigned int wv[4] = { r[k].x, r[k].y, r[k].z, r[k].w };
#pragma unroll
            for (int c2 = 0; c2 < 4; ++c2) {
                unsigned int word = wv[c2];
                int bb = (k * 4 + c2) << 5;
                while (word) {
                    int j = __ffs(word) - 1;
                    word &= word - 1;
                    u.s.nbr[idx++] = (unsigned short)(bb + j);
                }
            }
        }
        if (dg & 1) u.s.nbr[idx] = (unsigned short)N;   // sentinel -> adds 0
    }
    u.s.meta[t] = (start << 11) | dg;               // start<2^15, dg<2^11
    __syncthreads();                                        // A3 (nbr/meta/dtop)

    {   // sorted placement: descending degree groups, arrival order in bin
        int pos = s_dtop[dbin] + pib;
        u.s.perm[pos] = (unsigned short)t;
    }
    __syncthreads();                                        // A6 (perm visible)

    int v_node = u.s.perm[t];                       // this thread's node
    int mv = u.s.meta[v_node];
    int vdeg = mv & 2047;
    int vpstart = (mv >> 11) >> 1;
    int vpairs = (((mv & 2047) + 1) & ~1) >> 1;
    int lab_reg = s_lab[v_node];
    const unsigned int* nbr32 = (const unsigned int*)u.s.nbr;
    // wave-uniform max pairs (shfl reduce; no sort-order assumption)
    int wmax = vpairs;
#pragma unroll
    for (int m2 = 32; m2 >= 1; m2 >>= 1) wmax = max(wmax, __shfl_xor(wmax, m2));
    wmax = __builtin_amdgcn_readfirstlane(wmax);
    // iteration-invariant pair-words -> registers, chunk-skipped preload
    unsigned int pw[MAXP];
#pragma unroll
    for (int c = 0; c < MAXP / 4; ++c) {
        if (c * 4 < wmax) {
#pragma unroll
            for (int k = 0; k < 4; ++k) {
                int kk = c * 4 + k;
                pw[kk] = (kk < vpairs) ? nbr32[vpstart + kk] : SENT_PAIR;
            }
        } else {
#pragma unroll
            for (int k = 0; k < 4; ++k) pw[c * 4 + k] = SENT_PAIR;
        }
    }

    // ---- Phase B: 5 WL iterations ----
    int nfast = 0;                                  // fast-path feats counter
    for (int it = 0; it < NITER; ++it) {
        int ssum = 0;
#pragma unroll
        for (int c = 0; c < MAXP / 4; ++c) {        // wave-uniform chunk skip
            if (c * 4 < wmax) {
#pragma unroll
                for (int k = 0; k < 4; ++k) {
                    unsigned int pr = pw[c * 4 + k];
                    ssum += s_lab[pr & 0xFFFFu] + s_lab[pr >> 16];
                }
            }
        }
        for (int k = MAXP; k < vpairs; ++k) {       // rare high-deg fallback
            unsigned int pr = nbr32[vpstart + k];
            ssum += s_lab[pr & 0xFFFFu] + s_lab[pr >> 16];
        }
        float t1 = __fmul_rn(__fmul_rn(Kf, w0), (float)lab_reg);
        float t2 = __fmul_rn(w1, __fsub_rn(__fadd_rn((float)ssum, (float)vdeg), Kf));
        float h  = __fadd_rn(t1, t2);

        float mn = h, mx = h;
#pragma unroll
        for (int o = 32; o > 0; o >>= 1) {
            mn = fminf(mn, __shfl_down(mn, o));
            mx = fmaxf(mx, __shfl_down(mx, o));
        }
        if (lane == 0) { s_mn[w] = mn; s_mx[w] = mx; }
        __syncthreads();                                    // B1
        // all-wave redundant min/max combine -> registers (no 2nd barrier)
        float fmn, span;
        {
            float a = s_mn[lane & 15];
            float cmx = s_mx[lane & 15];
#pragma unroll
            for (int m2 = 8; m2 >= 1; m2 >>= 1) {
                a = fminf(a, __shfl_xor(a, m2));
                cmx = fmaxf(cmx, __shfl_xor(cmx, m2));
            }
            fmn = a;
            span = cmx - a;
        }
        float scale = (span > 0.f) ? (1023.0f / span) : 0.f;
        int bucket = min((int)((h - fmn) * scale), 1023);   // order-preserving
        int off_in = atomicAdd(&u.s.pb.hist[bucket], 1);
        __syncthreads();                                    // B3

        f = u.s.pb.hist[t];
#pragma unroll
        for (int d2 = 1; d2 < 64; d2 <<= 1) {
            int v = __shfl_up(f, d2);
            if (lane >= d2) f += v;
        }
        if (lane == 63) s_wsum[w] = f;
        __syncthreads();                                    // B4
        {   // all-wave redundant exclusive wave base -> register
            int vv = ((lane & 15) < w) ? s_wsum[lane & 15] : 0;
#pragma unroll
            for (int m2 = 1; m2 < 16; m2 <<= 1) vv += __shfl_xor(vv, m2);
            u.s.pb.scan[t] = f + vv;
        }
        __syncthreads();                                    // B6

        int bs = u.s.pb.scan[bucket] - u.s.pb.hist[bucket];
        int be = u.s.pb.scan[bucket];
        u.s.pb.grp[bs + off_in] = h;
        __syncthreads();                                    // B7

        int cr = bs;                // lower buckets strictly less (monotone map)
        int eq = 0;
        for (int k = bs; k < be; ++k) {
            float g = u.s.pb.grp[k];
            cr += (g < h);
            eq += (g == h);
        }
        if (eq > 1) s_anytie = it + 1;  // sentinel: stale iters self-invalidate
        u.s.pb.hist[t] = 0;             // re-zero for next iter (readers done pre-B7)
        s_lab[v_node] = cr;             // optimistic fast-path rank (dense iff no ties)
        __syncthreads();                                    // B9
        if (s_anytie == it + 1) {       // rare: dense-rank repair pass
            u.s.pb.flag[cr] = 1;        // class start (same class -> same cr)
            __syncthreads();                                // T1
            int f2 = u.s.pb.flag[t];
#pragma unroll
            for (int d2 = 1; d2 < 64; d2 <<= 1) {
                int v = __shfl_up(f2, d2);
                if (lane >= d2) f2 += v;
            }
            if (lane == 63) s_wsum[w] = f2;
            __syncthreads();                                // T2
            {   // all-wave redundant exclusive wave base -> register
                int vv = ((lane & 15) < w) ? s_wsum[lane & 15] : 0;
#pragma unroll
                for (int m2 = 1; m2 < 16; m2 <<= 1) vv += __shfl_xor(vv, m2);
                u.s.pb.scan[t] = f2 + vv;
            }
            u.s.pb.flag[t] = 0;         // own flag consumed above
            __syncthreads();                                // T4
            int rank = u.s.pb.scan[cr] - 1;
            s_lab[v_node] = rank;
            lab_reg = rank;
            atomicAdd(&s_feats[rank], 1u);
            __syncthreads();                                // T5: labels visible
        } else {
            lab_reg = cr;
            ++nfast;                    // permutation => every bin +1
        }
    }

    // ---- Phase C: feats out + fused diag[b] (int exact) ----
    unsigned int fv = s_feats[t] + (unsigned)nfast;
    feats[(size_t)b * N + t] = fv;
    int sq = (int)(fv * fv);
#pragma unroll
    for (int o = 32; o > 0; o >>= 1) sq += __shfl_down(sq, o);
    if (lane == 0) s_wsum[w] = sq;
    __syncthreads();
    if (t == 0) {
        int tot = 0;
#pragma unroll
        for (int k = 0; k < 16; ++k) tot += s_wsum[k];
        diag[b] = (float)tot;
    }
}

// gram+normalize fused: one block per row i; f_i staged in LDS; int dots
// exact. 1024 threads, 16 waves x 4 j's each (serial chain 4 iterations).
__global__ void __launch_bounds__(1024) gram_k(const unsigned int* __restrict__ feats,
                                               const float* __restrict__ diag,
                                               float* __restrict__ out) {
    __shared__ unsigned int s_fi[N];
    int i = blockIdx.x, t = threadIdx.x;
    int lane = t & 63, w = t >> 6;
    if (t < 256)
        ((uint4*)s_fi)[t] = ((const uint4*)(feats + (size_t)i * N))[t];
    __syncthreads();
    float di = diag[i];
#pragma unroll
    for (int jj = 0; jj < 4; ++jj) {
        int j = w * 4 + jj;
        const uint4* fj = (const uint4*)(feats + (size_t)j * N);
        const uint4* fi = (const uint4*)s_fi;
        int s = 0;
#pragma unroll
        for (int k = 0; k < 4; ++k) {
            uint4 vb = fj[lane + k * 64];
            uint4 va = fi[lane + k * 64];
            s += (int)(va.x * vb.x) + (int)(va.y * vb.y)
               + (int)(va.z * vb.z) + (int)(va.w * vb.w);
        }
#pragma unroll
        for (int off = 32; off > 0; off >>= 1) s += __shfl_down(s, off);
        if (lane == 0) out[i * B + j] = (float)s / sqrtf(di * diag[j]);
    }
}

extern "C" void kernel_launch(void* const* d_in, const int* in_sizes, int n_in,
                              void* d_out, int out_size, void* d_ws, size_t ws_size,
                              hipStream_t stream) {
    const int*   esrc = (const int*)d_in[0];
    const int*   edst = (const int*)d_in[1];
    const int*   lab0 = (const int*)d_in[2];
    const float* hw   = (const float*)d_in[3];

    char* ws = (char*)d_ws;
    unsigned int* feats = (unsigned int*)(ws + FEATS_OFF);
    float*        diag  = (float*)(ws + DIAG_OFF);

    wl_mega_k<<<B, 1024, 0, stream>>>(esrc, edst, lab0, hw, feats, diag);
    gram_k<<<B, 1024, 0, stream>>>(feats, diag, (float*)d_out);
}